// Round 10
// baseline (149.622 us; speedup 1.0000x reference)
//
#include <hip/hip_runtime.h>
#include <hip/hip_bf16.h>

// ScoreAttention on MI355X (gfx950).
// Pipeline: gn_stats_part+convert_w(tiled) -> gn_apply(tiled h) -> qkv_gemm(staged)
//           -> flash_part(x4 K-split) -> proj_merge_gemm(staged, fused merge)
// R23: flash v19 -- KVBLK 64->128 (iterations 16->8: loop/addressing/barrier-skew
// and dependency chain-tails paid half as often; staging cost per key unchanged;
// LDS 35.3KB, residency still register-capped at ~2 blocks/CU) + T5 setprio(1)
// around the compute phase (2+ independent blocks/CU = role diversity; m191
// measured +4-7% on attn in this regime). Evidence base: R16/R18/R21/R22
// falsified barrier/ordering theories -- the stall is per-wave dependency
// latency; only overhead-amortization and scheduler-priority remain.

typedef __attribute__((ext_vector_type(8))) __bf16 bf16x8;
typedef __attribute__((ext_vector_type(4))) float f32x4;
typedef __attribute__((ext_vector_type(2))) float f32x2;
typedef __attribute__((ext_vector_type(16))) float f32x16;
typedef __attribute__((ext_vector_type(2))) unsigned int uint32x2;

#define HW 4096
#define C 256
#define NH 8
#define HD 32
#define QSCALE 0.25505654f  /* log2(e)/sqrt(32) */
#define KST 36    /* flash K tile row stride */
#define VST2 132  /* flash V tile row stride (128 + 4 pad shorts) */
#define TST 36    /* GEMM LDS tile row stride (32 + 4 pad shorts) */
#define NSPLIT 4

__device__ inline unsigned short f2bf(float f) {
  union { float f; unsigned int u; } v; v.f = f;
  unsigned int u = v.u;
  return (unsigned short)((u + 0x7fffu + ((u >> 16) & 1u)) >> 16);
}

__device__ inline bf16x8 load8(const unsigned short* p) {
  bf16x8 v;
  __builtin_memcpy(&v, __builtin_assume_aligned(p, 16), 16);
  return v;
}

// 8B-aligned LDS read of 8 bf16 as two b64s
__device__ inline bf16x8 load8_lds(const unsigned short* p) {
  uint2 a = *(const uint2*)__builtin_assume_aligned(p, 8);
  uint2 b = *(const uint2*)__builtin_assume_aligned(p + 4, 8);
  union { uint4 u; bf16x8 v; } cv;
  cv.u = make_uint4(a.x, a.y, b.x, b.y);
  return cv.v;
}

__device__ inline unsigned int fbits(float f) {
  unsigned int u; __builtin_memcpy(&u, &f, 4); return u;
}
__device__ inline float bits2f(unsigned int u) {
  float f; __builtin_memcpy(&f, &u, 4); return f;
}

// pack two f32 -> two bf16 in one dword (round via +0x8000)
__device__ inline unsigned int pack_bf2(float lo, float hi) {
  return __builtin_amdgcn_perm(fbits(hi) + 0x8000u, fbits(lo) + 0x8000u, 0x07060302u);
}
// truncating pack (1 instr) — for P, where the error budget is generous
__device__ inline unsigned int pack_bf2t(float lo, float hi) {
  return __builtin_amdgcn_perm(fbits(hi), fbits(lo), 0x07060302u);
}

// accumulate 8 bf16 partials (one uint4 of po) into f32[8]
__device__ inline void acc_po(const uint4& v, float* a) {
  a[0] += bits2f(v.x << 16);  a[1] += bits2f(v.x & 0xffff0000u);
  a[2] += bits2f(v.y << 16);  a[3] += bits2f(v.y & 0xffff0000u);
  a[4] += bits2f(v.z << 16);  a[5] += bits2f(v.z & 0xffff0000u);
  a[6] += bits2f(v.w << 16);  a[7] += bits2f(v.w & 0xffff0000u);
}

// ---------------- GroupNorm partial stats (blocks 0..255) + weight conv (256..511)
__global__ __launch_bounds__(256) void gn_stats_part(const float* __restrict__ x,
                                                     float* __restrict__ parts,
                                                     const float* __restrict__ wq,
                                                     const float* __restrict__ wp,
                                                     unsigned short* __restrict__ wq_t,
                                                     unsigned short* __restrict__ wp_t) {
  if (blockIdx.x >= 256) {
    int d = (blockIdx.x - 256) * 1024 + threadIdx.x * 4;   // dest-linear index
    const float* src;
    unsigned short* dst;
    int dd;
    if (d < 196608) { dd = d; src = wq; dst = wq_t; }
    else            { dd = d - 196608; src = wp; dst = wp_t; }
    int tile = dd >> 11, rem = dd & 2047;
    int row = rem >> 5, col = rem & 31;
    int mb = tile >> 3, kb = tile & 7;
    int o = mb * 64 + row, c = kb * 32 + col;
    float4 v = *(const float4*)(src + (size_t)o * 256 + c);
    uint2 pk;
    pk.x = (unsigned int)f2bf(v.x) | ((unsigned int)f2bf(v.y) << 16);
    pk.y = (unsigned int)f2bf(v.z) | ((unsigned int)f2bf(v.w) << 16);
    *(uint2*)(dst + dd) = pk;
    return;
  }
  int i = blockIdx.x;
  const float4* p4 = (const float4*)(x + (size_t)i * 8192);
  int t = threadIdx.x;
  float s = 0.f, ss = 0.f;
  for (int k = t; k < 2048; k += 256) {
    float4 v = p4[k];
    s  += v.x + v.y + v.z + v.w;
    ss += v.x*v.x + v.y*v.y + v.z*v.z + v.w*v.w;
  }
  for (int m = 32; m >= 1; m >>= 1) {
    s  += __shfl_down(s, m, 64);
    ss += __shfl_down(ss, m, 64);
  }
  __shared__ float red[8];
  int w = t >> 6;
  if ((t & 63) == 0) { red[w] = s; red[w + 4] = ss; }
  __syncthreads();
  if (t == 0) {
    parts[i]       = red[0] + red[1] + red[2] + red[3];
    parts[256 + i] = red[4] + red[5] + red[6] + red[7];
  }
}

// ---------------- GroupNorm apply + transpose -> tiled h layout
__global__ __launch_bounds__(256) void gn_apply(const float* __restrict__ x,
                                                const float* __restrict__ parts,
                                                const float* __restrict__ gamma,
                                                const float* __restrict__ beta,
                                                unsigned short* __restrict__ h_t) {
  __shared__ float tile[64][65];
  __shared__ float gmean[8], grstd[8];
  int b = blockIdx.z, c0 = blockIdx.y * 64, s0 = blockIdx.x * 64;
  int t = threadIdx.x;
  if (t < 8) {
    int bg = b * 32 + (c0 >> 3) + t;
    float s  = (parts[4*bg] + parts[4*bg+1]) + (parts[4*bg+2] + parts[4*bg+3]);
    float ss = (parts[256+4*bg] + parts[256+4*bg+1]) + (parts[256+4*bg+2] + parts[256+4*bg+3]);
    float mean = s * (1.0f / 32768.0f);
    float var  = ss * (1.0f / 32768.0f) - mean * mean;
    gmean[t] = mean;
    grstd[t] = rsqrtf(var + 1e-5f);
  }
  const float* xb = x + ((size_t)b * C + c0) * HW + s0;
  #pragma unroll
  for (int k = 0; k < 16; k++) {
    int e = k * 256 + t;
    int i = e >> 6, j = e & 63;
    tile[i][j] = xb[(size_t)i * HW + j];
  }
  __syncthreads();
  // tiled store: base tile (sblk = s0>>6, kblk = c0>>5)
  unsigned short* hb = h_t + (size_t)b * HW * C +
                       ((size_t)(s0 >> 6) * 8 + (c0 >> 5)) * 2048;
  #pragma unroll
  for (int k = 0; k < 16; k++) {
    int e = k * 256 + t;
    int jr = e >> 6, ir = e & 63;
    int c = c0 + ir, gl = ir >> 3;
    float v = (tile[ir][jr] - gmean[gl]) * grstd[gl] * gamma[c] + beta[c];
    hb[(ir >> 5) * 2048 + jr * 32 + (ir & 31)] = f2bf(v);
  }
}

// ---------------- QKV GEMM v3: 128x64 tiles, staged tiled operands, dbuf LDS
__global__ __launch_bounds__(256) void qkv_gemm(const unsigned short* __restrict__ wq_t,
                                                const unsigned short* __restrict__ h_t,
                                                const float* __restrict__ b_qkv,
                                                unsigned short* __restrict__ q_t,
                                                unsigned short* __restrict__ k_t,
                                                unsigned short* __restrict__ v_t) {
  int t = threadIdx.x;
  int lane = t & 63, w = t >> 6;
  int quad = lane >> 4, l16 = lane & 15;
  int m0 = blockIdx.y * 128;
  int n0 = blockIdx.x * 64;
  int b  = blockIdx.z;

  __shared__ __align__(16) unsigned short at2[2][128 * TST];
  __shared__ __align__(16) unsigned short bt2[2][64 * TST];

  const uint4* Ag = (const uint4*)(wq_t + (size_t)(blockIdx.y * 2) * 8 * 2048);
  const uint4* Bg = (const uint4*)(h_t + (size_t)b * HW * C + (size_t)blockIdx.x * 8 * 2048);
  int lrow = t >> 2, lcol = (t & 3) * 8;

  f32x4 acc[2][4];
  #pragma unroll
  for (int sl = 0; sl < 2; sl++)
    #pragma unroll
    for (int nb = 0; nb < 4; nb++) acc[sl][nb] = (f32x4){0.f, 0.f, 0.f, 0.f};

  uint4 areg0 = Ag[t];
  uint4 areg1 = Ag[8 * 256 + t];
  uint4 breg  = Bg[t];
  int phase = 0;
  for (int k = 0; k < 8; k++, phase ^= 1) {
    unsigned short* ap = &at2[phase][0];
    unsigned short* bp = &bt2[phase][0];
    *(uint2*)(ap + lrow * TST + lcol)            = make_uint2(areg0.x, areg0.y);
    *(uint2*)(ap + lrow * TST + lcol + 4)        = make_uint2(areg0.z, areg0.w);
    *(uint2*)(ap + (64 + lrow) * TST + lcol)     = make_uint2(areg1.x, areg1.y);
    *(uint2*)(ap + (64 + lrow) * TST + lcol + 4) = make_uint2(areg1.z, areg1.w);
    *(uint2*)(bp + lrow * TST + lcol)            = make_uint2(breg.x, breg.y);
    *(uint2*)(bp + lrow * TST + lcol + 4)        = make_uint2(breg.z, breg.w);
    int kn = (k < 7) ? k + 1 : 7;
    areg0 = Ag[kn * 256 + t];
    areg1 = Ag[(8 + kn) * 256 + t];
    breg  = Bg[kn * 256 + t];
    __syncthreads();
    bf16x8 a0 = load8_lds(ap + (w * 32 + l16) * TST + quad * 8);
    bf16x8 a1 = load8_lds(ap + (w * 32 + 16 + l16) * TST + quad * 8);
    #pragma unroll
    for (int nb = 0; nb < 4; nb++) {
      bf16x8 bb = load8_lds(bp + (nb * 16 + l16) * TST + quad * 8);
      acc[0][nb] = __builtin_amdgcn_mfma_f32_16x16x32_bf16(a0, bb, acc[0][nb], 0, 0, 0);
      acc[1][nb] = __builtin_amdgcn_mfma_f32_16x16x32_bf16(a1, bb, acc[1][nb], 0, 0, 0);
    }
  }

  int seg = m0 >> 8;   // 128-row blocks never straddle a Q/K/V segment
  #pragma unroll
  for (int sl = 0; sl < 2; sl++) {
    int o0 = m0 + w * 32 + sl * 16 + quad * 4;
    #pragma unroll
    for (int nb = 0; nb < 4; nb++) {
      int s = n0 + nb * 16 + l16;
      if (seg == 2) {
        #pragma unroll
        for (int r = 0; r < 4; r++)
          v_t[((size_t)b * C + ((o0 + r) - 512)) * HW + s] = f2bf(acc[sl][nb][r] + b_qkv[o0 + r]);
      } else {
        float sc = seg ? 1.0f : QSCALE;
        float v0 = (acc[sl][nb][0] + b_qkv[o0])     * sc;
        float v1 = (acc[sl][nb][1] + b_qkv[o0 + 1]) * sc;
        float v2 = (acc[sl][nb][2] + b_qkv[o0 + 2]) * sc;
        float v3 = (acc[sl][nb][3] + b_qkv[o0 + 3]) * sc;
        int oc = o0 & 255, h = oc >> 5, d = oc & 31;
        unsigned short* dst = seg ? k_t : q_t;
        uint2 dd;
        dd.x = pack_bf2(v0, v1);
        dd.y = pack_bf2(v2, v3);
        *(uint2*)(dst + (((size_t)b * NH + h) * HW + s) * HD + d) = dd;
      }
    }
  }
}

// softmax on S (one 32-key block): exp2, accumulate row-sum, and build the two
// PV B-operand fragments (keys 0..15 / 16..31) entirely in registers.
// Lane (n=query, hi) holds S[key=(r&3)+8*(r>>2)+4*hi][n] for r=0..15.
// B-fragment needs keys 8*hi+e per lane -> cross-hi exchange via permlane32_swap.
__device__ __forceinline__ void softmax_frag(const f32x16& S, f32x2& ps2,
                                             bf16x8& f0, bf16x8& f1) {
  float p[16];
  #pragma unroll
  for (int r = 0; r < 16; r++)
    p[r] = __builtin_amdgcn_exp2f(S[r]);
  f32x2 t0 = (f32x2){p[0], p[1]} + (f32x2){p[2], p[3]};
  f32x2 t1 = (f32x2){p[4], p[5]} + (f32x2){p[6], p[7]};
  f32x2 t2 = (f32x2){p[8], p[9]} + (f32x2){p[10], p[11]};
  f32x2 t3 = (f32x2){p[12], p[13]} + (f32x2){p[14], p[15]};
  ps2 += (t0 + t1) + (t2 + t3);
  unsigned int c0 = pack_bf2t(p[0],  p[1]);
  unsigned int c1 = pack_bf2t(p[2],  p[3]);
  unsigned int c2 = pack_bf2t(p[4],  p[5]);
  unsigned int c3 = pack_bf2t(p[6],  p[7]);
  unsigned int c4 = pack_bf2t(p[8],  p[9]);
  unsigned int c5 = pack_bf2t(p[10], p[11]);
  unsigned int c6 = pack_bf2t(p[12], p[13]);
  unsigned int c7 = pack_bf2t(p[14], p[15]);
  uint32x2 s02 = __builtin_amdgcn_permlane32_swap(c0, c2, false, false);
  uint32x2 s13 = __builtin_amdgcn_permlane32_swap(c1, c3, false, false);
  uint32x2 s46 = __builtin_amdgcn_permlane32_swap(c4, c6, false, false);
  uint32x2 s57 = __builtin_amdgcn_permlane32_swap(c5, c7, false, false);
  union { uint4 u; bf16x8 v; } a, b;
  a.u = make_uint4(s02.x, s13.x, s02.y, s13.y);
  b.u = make_uint4(s46.x, s57.x, s46.y, s57.y);
  f0 = a.v;
  f1 = b.v;
}

// ---------------- Flash v19: grid (bh=16, qtile256=16, split=4); 64 q/wave;
// KVBLK=128 per iteration (8 iters), setprio(1) around the compute phase.
__global__ __launch_bounds__(256) void flash_part(const unsigned short* __restrict__ q_t,
                                                  const unsigned short* __restrict__ k_t,
                                                  const unsigned short* __restrict__ v_t,
                                                  unsigned short* __restrict__ po,
                                                  float* __restrict__ pl,
                                                  int jspan) {
  int t = threadIdx.x;
  int lane = t & 63, w = t >> 6;
  int n = lane & 31, hi = lane >> 5, hi8 = hi * 8;
  int bh = blockIdx.x, b = bh >> 3, h = bh & 7;
  int m0 = blockIdx.y * 256 + w * 64;   // wave owns queries [m0, m0+64)
  int z = blockIdx.z;

  __shared__ __align__(16) unsigned short kt2[2][128 * KST];
  __shared__ __align__(16) unsigned short vt2[2][32 * VST2];

  const unsigned short* Q  = q_t + (size_t)bh * HW * HD;
  const unsigned short* Kg = k_t + (size_t)bh * HW * HD;
  const unsigned short* Vg = v_t + ((size_t)b * C + h * HD) * HW;

  bf16x8 qa0 = load8(Q + (size_t)(m0 + n) * HD + hi8);
  bf16x8 qa1 = load8(Q + (size_t)(m0 + n) * HD + 16 + hi8);
  bf16x8 qb0 = load8(Q + (size_t)(m0 + 32 + n) * HD + hi8);
  bf16x8 qb1 = load8(Q + (size_t)(m0 + 32 + n) * HD + 16 + hi8);

  int kkey = t >> 2, kseg = (t & 3) * 8;
  int vd   = t >> 3, vseg = (t & 7) * 8;
  const unsigned short* kgp = Kg + (size_t)kkey * HD + kseg;
  const unsigned short* vgp = Vg + (size_t)vd * HW + vseg;

  f32x2 psa = (f32x2){0.f, 0.f};
  f32x2 psb = (f32x2){0.f, 0.f};
  f32x16 oTa = (f32x16){0.f,0.f,0.f,0.f,0.f,0.f,0.f,0.f,0.f,0.f,0.f,0.f,0.f,0.f,0.f,0.f};
  f32x16 oTb = (f32x16){0.f,0.f,0.f,0.f,0.f,0.f,0.f,0.f,0.f,0.f,0.f,0.f,0.f,0.f,0.f,0.f};
  const f32x16 zero16 = (f32x16){0.f,0.f,0.f,0.f,0.f,0.f,0.f,0.f,0.f,0.f,0.f,0.f,0.f,0.f,0.f,0.f};

  int jbase = z * jspan, jend = jbase + jspan;
  uint4 kreg0 = *(const uint4*)(kgp + (size_t)jbase * HD);
  uint4 kreg1 = *(const uint4*)(kgp + (size_t)(jbase + 64) * HD);
  uint4 vreg0 = *(const uint4*)(vgp + jbase);
  uint4 vreg1 = *(const uint4*)(vgp + jbase + 64);

  int phase = 0;
  for (int j0 = jbase; j0 < jend; j0 += 128, phase ^= 1) {
    unsigned short* ktp = &kt2[phase][0];
    unsigned short* vtp = &vt2[phase][0];
    *(uint2*)(ktp + kkey * KST + kseg)            = make_uint2(kreg0.x, kreg0.y);
    *(uint2*)(ktp + kkey * KST + kseg + 4)        = make_uint2(kreg0.z, kreg0.w);
    *(uint2*)(ktp + (64 + kkey) * KST + kseg)     = make_uint2(kreg1.x, kreg1.y);
    *(uint2*)(ktp + (64 + kkey) * KST + kseg + 4) = make_uint2(kreg1.z, kreg1.w);
    *(uint2*)(vtp + vd * VST2 + vseg)             = make_uint2(vreg0.x, vreg0.y);
    *(uint2*)(vtp + vd * VST2 + vseg + 4)         = make_uint2(vreg0.z, vreg0.w);
    *(uint2*)(vtp + vd * VST2 + 64 + vseg)        = make_uint2(vreg1.x, vreg1.y);
    *(uint2*)(vtp + vd * VST2 + 64 + vseg + 4)    = make_uint2(vreg1.z, vreg1.w);
    int jn = (j0 + 128 < jend) ? (j0 + 128) : jbase;
    kreg0 = *(const uint4*)(kgp + (size_t)jn * HD);
    kreg1 = *(const uint4*)(kgp + (size_t)(jn + 64) * HD);
    vreg0 = *(const uint4*)(vgp + jn);
    vreg1 = *(const uint4*)(vgp + jn + 64);
    // barrier without the implicit vmcnt(0) drain (R22, perf-neutral, kept):
    // LDS ordering needs only lgkmcnt; prefetch stays in flight.
    asm volatile("s_waitcnt lgkmcnt(0)" ::: "memory");
    __builtin_amdgcn_s_barrier();

    __builtin_amdgcn_s_setprio(1);
    #pragma unroll
    for (int half = 0; half < 2; half++) {
      const unsigned short* kr0 = ktp + (half * 64 + n) * KST;
      const unsigned short* kr1 = ktp + (half * 64 + 32 + n) * KST;
      bf16x8 ka0 = load8_lds(kr0 + hi8);
      bf16x8 ka1 = load8_lds(kr0 + 16 + hi8);
      bf16x8 kb0 = load8_lds(kr1 + hi8);
      bf16x8 kb1 = load8_lds(kr1 + 16 + hi8);

      // ---- query group a
      f32x16 S0 = __builtin_amdgcn_mfma_f32_32x32x16_bf16(ka1, qa1, zero16, 0, 0, 0);
      S0 = __builtin_amdgcn_mfma_f32_32x32x16_bf16(ka0, qa0, S0, 0, 0, 0);
      f32x16 S1 = __builtin_amdgcn_mfma_f32_32x32x16_bf16(kb1, qa1, zero16, 0, 0, 0);
      S1 = __builtin_amdgcn_mfma_f32_32x32x16_bf16(kb0, qa0, S1, 0, 0, 0);
      bf16x8 pf0, pf1, pf2, pf3;
      softmax_frag(S0, psa, pf0, pf1);
      softmax_frag(S1, psa, pf2, pf3);
      const unsigned short* vrow = vtp + n * VST2 + half * 64;
      bf16x8 vf0 = load8_lds(vrow + hi8);
      bf16x8 vf1 = load8_lds(vrow + 16 + hi8);
      bf16x8 vf2 = load8_lds(vrow + 32 + hi8);
      bf16x8 vf3 = load8_lds(vrow + 48 + hi8);
      oTa = __builtin_amdgcn_mfma_f32_32x32x16_bf16(vf0, pf0, oTa, 0, 0, 0);
      oTa = __builtin_amdgcn_mfma_f32_32x32x16_bf16(vf1, pf1, oTa, 0, 0, 0);
      oTa = __builtin_amdgcn_mfma_f32_32x32x16_bf16(vf2, pf2, oTa, 0, 0, 0);
      oTa = __builtin_amdgcn_mfma_f32_32x32x16_bf16(vf3, pf3, oTa, 0, 0, 0);

      // ---- query group b (reuses ka*/kb*/vf* fragments)
      f32x16 T0 = __builtin_amdgcn_mfma_f32_32x32x16_bf16(ka1, qb1, zero16, 0, 0, 0);
      T0 = __builtin_amdgcn_mfma_f32_32x32x16_bf16(ka0, qb0, T0, 0, 0, 0);
      f32x16 T1 = __builtin_amdgcn_mfma_f32_32x32x16_bf16(kb1, qb1, zero16, 0, 0, 0);
      T1 = __builtin_amdgcn_mfma_f32_32x32x16_bf16(kb0, qb0, T1, 0, 0, 0);
      softmax_frag(T0, psb, pf0, pf1);
      softmax_frag(T1, psb, pf2, pf3);
      oTb = __builtin_amdgcn_mfma_f32_32x32x16_bf16(vf0, pf0, oTb, 0, 0, 0);
      oTb = __builtin_amdgcn_mfma_f32_32x32x16_bf16(vf1, pf1, oTb, 0, 0, 0);
      oTb = __builtin_amdgcn_mfma_f32_32x32x16_bf16(vf2, pf2, oTb, 0, 0, 0);
      oTb = __builtin_amdgcn_mfma_f32_32x32x16_bf16(vf3, pf3, oTb, 0, 0, 0);
    }
    __builtin_amdgcn_s_setprio(0);
  }

  float psuma = psa.x + psa.y;
  psuma += __shfl_xor(psuma, 32, 64);
  float psumb = psb.x + psb.y;
  psumb += __shfl_xor(psumb, 32, 64);

  unsigned short* pra = po + (((size_t)z * 16 + bh) * HW + (m0 + n)) * 32;
  unsigned short* prb = po + (((size_t)z * 16 + bh) * HW + (m0 + 32 + n)) * 32;
  #pragma unroll
  for (int g = 0; g < 4; g++) {
    uint2 dd;
    dd.x = pack_bf2(oTa[4 * g], oTa[4 * g + 1]);
    dd.y = pack_bf2(oTa[4 * g + 2], oTa[4 * g + 3]);
    *(uint2*)(pra + g * 8 + hi * 4) = dd;
    uint2 de;
    de.x = pack_bf2(oTb[4 * g], oTb[4 * g + 1]);
    de.y = pack_bf2(oTb[4 * g + 2], oTb[4 * g + 3]);
    *(uint2*)(prb + g * 8 + hi * 4) = de;
  }
  if (lane < 32) {
    pl[((size_t)z * 16 + bh) * HW + m0 + n] = psuma;
    pl[((size_t)z * 16 + bh) * HW + m0 + 32 + n] = psumb;
  }
}

// ---------------- Proj GEMM v3: fused split-K merge in B-staging + bias + residual
__global__ __launch_bounds__(256) void proj_gemm(const unsigned short* __restrict__ wp_t,
                                                 const unsigned short* __restrict__ po,
                                                 const float* __restrict__ pl,
                                                 const float* __restrict__ b_proj,
                                                 const float* __restrict__ x,
                                                 float* __restrict__ out) {
  int t = threadIdx.x;
  int lane = t & 63, w = t >> 6;
  int quad = lane >> 4, l16 = lane & 15;
  int m0 = blockIdx.y * 64 + w * 16;
  int n0 = blockIdx.x * 64;
  int b  = blockIdx.z;

  __shared__ __align__(16) unsigned short at2[2][64 * TST];
  __shared__ __align__(16) unsigned short bt2[2][64 * TST];

  const uint4* Ag  = (const uint4*)(wp_t + (size_t)blockIdx.y * 8 * 2048);
  const uint4* po4 = (const uint4*)po;
  int lrow = t >> 2, lcol = (t & 3) * 8;
  int s = n0 + lrow;
  const size_t zs4 = (size_t)16 * HW * 4;   // po uint4 stride per split
  const size_t zsl = (size_t)16 * HW;       // pl stride per split

  f32x4 acc[4];
  #pragma unroll
  for (int nb = 0; nb < 4; nb++) acc[nb] = (f32x4){0.f, 0.f, 0.f, 0.f};

  uint4 areg = Ag[t];
  // prefetch po/pl for k=0 (head h=0 -> bh = b*8)
  size_t pidx = ((size_t)(b * 8) * HW + s) * 4 + (t & 3);
  size_t lidx = (size_t)(b * 8) * HW + s;
  uint4 pz0 = po4[pidx];
  uint4 pz1 = po4[zs4 + pidx];
  uint4 pz2 = po4[2 * zs4 + pidx];
  uint4 pz3 = po4[3 * zs4 + pidx];
  float l0 = pl[lidx], l1 = pl[zsl + lidx], l2 = pl[2 * zsl + lidx], l3 = pl[3 * zsl + lidx];

  int phase = 0;
  for (int k = 0; k < 8; k++, phase ^= 1) {
    unsigned short* ap = &at2[phase][0];
    unsigned short* bp = &bt2[phase][0];
    *(uint2*)(ap + lrow * TST + lcol)     = make_uint2(areg.x, areg.y);
    *(uint2*)(ap + lrow * TST + lcol + 4) = make_uint2(areg.z, areg.w);
    // merge 4 split partials -> bf16 B-tile row chunk (same arithmetic/order
    // as the old merge_parts kernel)
    {
      float a[8] = {0.f,0.f,0.f,0.f,0.f,0.f,0.f,0.f};
      acc_po(pz0, a);
      acc_po(pz1, a);
      acc_po(pz2, a);
      acc_po(pz3, a);
      float inv = 1.0f / (((l0 + l1) + l2) + l3);
      uint2 d0, d1;
      d0.x = pack_bf2(a[0] * inv, a[1] * inv);
      d0.y = pack_bf2(a[2] * inv, a[3] * inv);
      d1.x = pack_bf2(a[4] * inv, a[5] * inv);
      d1.y = pack_bf2(a[6] * inv, a[7] * inv);
      *(uint2*)(bp + lrow * TST + lcol)     = d0;
      *(uint2*)(bp + lrow * TST + lcol + 4) = d1;
    }
    int kn = (k < 7) ? k + 1 : 7;
    areg = Ag[kn * 256 + t];
    size_t pidxn = ((size_t)(b * 8 + kn) * HW + s) * 4 + (t & 3);
    size_t lidxn = (size_t)(b * 8 + kn) * HW + s;
    pz0 = po4[pidxn];
    pz1 = po4[zs4 + pidxn];
    pz2 = po4[2 * zs4 + pidxn];
    pz3 = po4[3 * zs4 + pidxn];
    l0 = pl[lidxn]; l1 = pl[zsl + lidxn]; l2 = pl[2 * zsl + lidxn]; l3 = pl[3 * zsl + lidxn];
    __syncthreads();
    bf16x8 a = load8_lds(ap + (w * 16 + l16) * TST + quad * 8);
    #pragma unroll
    for (int nb = 0; nb < 4; nb++) {
      bf16x8 bb = load8_lds(bp + (nb * 16 + l16) * TST + quad * 8);
      acc[nb] = __builtin_amdgcn_mfma_f32_16x16x32_bf16(a, bb, acc[nb], 0, 0, 0);
    }
  }
  #pragma unroll
  for (int nb = 0; nb < 4; nb++) {
    int so = n0 + nb * 16 + l16;
    #pragma unroll
    for (int r = 0; r < 4; r++) {
      int o = m0 + quad * 4 + r;
      size_t idx = ((size_t)b * C + o) * HW + so;
      out[idx] = acc[nb][r] + b_proj[o] + x[idx];
    }
  }
}

extern "C" void kernel_launch(void* const* d_in, const int* in_sizes, int n_in,
                              void* d_out, int out_size, void* d_ws, size_t ws_size,
                              hipStream_t stream) {
  const float* x      = (const float*)d_in[0];
  const float* w_qkv  = (const float*)d_in[1];
  const float* b_qkv  = (const float*)d_in[2];
  const float* w_proj = (const float*)d_in[3];
  const float* b_proj = (const float*)d_in[4];
  const float* gamma  = (const float*)d_in[5];
  const float* beta   = (const float*)d_in[6];
  float* out = (float*)d_out;

  char* ws = (char*)d_ws;
  float*          parts = (float*)ws;                          // 2 KB
  unsigned short* wq_t  = (unsigned short*)(ws + 4096);        // 384 KB (tiled)
  unsigned short* wp_t  = (unsigned short*)(ws + 397312);      // 128 KB (tiled)
  unsigned short* h_t   = (unsigned short*)(ws + 528384);      // 4 MB tiled
  unsigned short* q_t   = (unsigned short*)(ws + 4722688);     // 4 MB [bh][s][d]
  unsigned short* k_t   = (unsigned short*)(ws + 8916992);     // 4 MB [bh][s][d]
  unsigned short* v_t   = (unsigned short*)(ws + 13111296);    // 4 MB [b][c][s]
  unsigned short* po    = (unsigned short*)(ws + 17305600);    // 16 MB (4 splits, bf16)
  float*          pl    = (float*)(ws + 34082816);             // 1 MB (4 splits)

  gn_stats_part<<<512, 256, 0, stream>>>(x, parts, w_qkv, w_proj, wq_t, wp_t);
  gn_apply<<<dim3(64, 4, 2), 256, 0, stream>>>(x, parts, gamma, beta, h_t);
  qkv_gemm<<<dim3(64, 6, 2), 256, 0, stream>>>(wq_t, h_t, b_qkv, q_t, k_t, v_t);
  flash_part<<<dim3(16, 16, NSPLIT), 256, 0, stream>>>(q_t, k_t, v_t, po, pl, HW / NSPLIT);
  proj_gemm<<<dim3(64, 4, 2), 256, 0, stream>>>(wp_t, po, pl, b_proj, x, out);
}

// Round 11
// 146.467 us; speedup vs baseline: 1.0215x; 1.0215x over previous
//
#include <hip/hip_runtime.h>
#include <hip/hip_bf16.h>

// ScoreAttention on MI355X (gfx950).
// Pipeline: gn_stats_part+convert_w(tiled) -> gn_apply(tiled h) -> qkv_gemm(staged)
//           -> flash_part(x4 K-split) -> proj_merge_gemm(staged, fused merge)
// R24: REVERT to measured-best (R20, 147.10us): flash v15 (QBLK=64/wave,
// KVBLK=64, plain __syncthreads dbuf loop), qkv 128x64, coalesced weight conv,
// fused proj-merge. R23's KVBLK=128+setprio regressed (63.9us flash). Falsified
// on flash: occupancy x2, async-split x2, no-LDS, barrier-drain removal,
// tile-size x2, setprio. Residual = per-wave exp2->pack->permlane->MFMA chain
// latency (~60% VALU-issue efficiency at 4 waves/SIMD) -- structure's floor.

typedef __attribute__((ext_vector_type(8))) __bf16 bf16x8;
typedef __attribute__((ext_vector_type(4))) float f32x4;
typedef __attribute__((ext_vector_type(2))) float f32x2;
typedef __attribute__((ext_vector_type(16))) float f32x16;
typedef __attribute__((ext_vector_type(2))) unsigned int uint32x2;

#define HW 4096
#define C 256
#define NH 8
#define HD 32
#define QSCALE 0.25505654f  /* log2(e)/sqrt(32) */
#define KST 36   /* flash K tile row stride */
#define VST 68   /* flash V tile row stride */
#define TST 36   /* GEMM LDS tile row stride (32 + 4 pad shorts) */
#define NSPLIT 4

__device__ inline unsigned short f2bf(float f) {
  union { float f; unsigned int u; } v; v.f = f;
  unsigned int u = v.u;
  return (unsigned short)((u + 0x7fffu + ((u >> 16) & 1u)) >> 16);
}

__device__ inline bf16x8 load8(const unsigned short* p) {
  bf16x8 v;
  __builtin_memcpy(&v, __builtin_assume_aligned(p, 16), 16);
  return v;
}

// 8B-aligned LDS read of 8 bf16 as two b64s
__device__ inline bf16x8 load8_lds(const unsigned short* p) {
  uint2 a = *(const uint2*)__builtin_assume_aligned(p, 8);
  uint2 b = *(const uint2*)__builtin_assume_aligned(p + 4, 8);
  union { uint4 u; bf16x8 v; } cv;
  cv.u = make_uint4(a.x, a.y, b.x, b.y);
  return cv.v;
}

__device__ inline unsigned int fbits(float f) {
  unsigned int u; __builtin_memcpy(&u, &f, 4); return u;
}
__device__ inline float bits2f(unsigned int u) {
  float f; __builtin_memcpy(&f, &u, 4); return f;
}

// pack two f32 -> two bf16 in one dword (round via +0x8000)
__device__ inline unsigned int pack_bf2(float lo, float hi) {
  return __builtin_amdgcn_perm(fbits(hi) + 0x8000u, fbits(lo) + 0x8000u, 0x07060302u);
}
// truncating pack (1 instr) — for P, where the error budget is generous
__device__ inline unsigned int pack_bf2t(float lo, float hi) {
  return __builtin_amdgcn_perm(fbits(hi), fbits(lo), 0x07060302u);
}

// accumulate 8 bf16 partials (one uint4 of po) into f32[8]
__device__ inline void acc_po(const uint4& v, float* a) {
  a[0] += bits2f(v.x << 16);  a[1] += bits2f(v.x & 0xffff0000u);
  a[2] += bits2f(v.y << 16);  a[3] += bits2f(v.y & 0xffff0000u);
  a[4] += bits2f(v.z << 16);  a[5] += bits2f(v.z & 0xffff0000u);
  a[6] += bits2f(v.w << 16);  a[7] += bits2f(v.w & 0xffff0000u);
}

// ---------------- GroupNorm partial stats (blocks 0..255) + weight conv (256..511)
// weight conv: destination-linear -- float4 source read + uint2 dest write,
// both coalesced. f2bf rounding bit-identical.
__global__ __launch_bounds__(256) void gn_stats_part(const float* __restrict__ x,
                                                     float* __restrict__ parts,
                                                     const float* __restrict__ wq,
                                                     const float* __restrict__ wp,
                                                     unsigned short* __restrict__ wq_t,
                                                     unsigned short* __restrict__ wp_t) {
  if (blockIdx.x >= 256) {
    int d = (blockIdx.x - 256) * 1024 + threadIdx.x * 4;   // dest-linear index
    const float* src;
    unsigned short* dst;
    int dd;
    if (d < 196608) { dd = d; src = wq; dst = wq_t; }
    else            { dd = d - 196608; src = wp; dst = wp_t; }
    int tile = dd >> 11, rem = dd & 2047;
    int row = rem >> 5, col = rem & 31;
    int mb = tile >> 3, kb = tile & 7;
    int o = mb * 64 + row, c = kb * 32 + col;
    float4 v = *(const float4*)(src + (size_t)o * 256 + c);
    uint2 pk;
    pk.x = (unsigned int)f2bf(v.x) | ((unsigned int)f2bf(v.y) << 16);
    pk.y = (unsigned int)f2bf(v.z) | ((unsigned int)f2bf(v.w) << 16);
    *(uint2*)(dst + dd) = pk;
    return;
  }
  int i = blockIdx.x;
  const float4* p4 = (const float4*)(x + (size_t)i * 8192);
  int t = threadIdx.x;
  float s = 0.f, ss = 0.f;
  for (int k = t; k < 2048; k += 256) {
    float4 v = p4[k];
    s  += v.x + v.y + v.z + v.w;
    ss += v.x*v.x + v.y*v.y + v.z*v.z + v.w*v.w;
  }
  for (int m = 32; m >= 1; m >>= 1) {
    s  += __shfl_down(s, m, 64);
    ss += __shfl_down(ss, m, 64);
  }
  __shared__ float red[8];
  int w = t >> 6;
  if ((t & 63) == 0) { red[w] = s; red[w + 4] = ss; }
  __syncthreads();
  if (t == 0) {
    parts[i]       = red[0] + red[1] + red[2] + red[3];
    parts[256 + i] = red[4] + red[5] + red[6] + red[7];
  }
}

// ---------------- GroupNorm apply + transpose -> tiled h layout
__global__ __launch_bounds__(256) void gn_apply(const float* __restrict__ x,
                                                const float* __restrict__ parts,
                                                const float* __restrict__ gamma,
                                                const float* __restrict__ beta,
                                                unsigned short* __restrict__ h_t) {
  __shared__ float tile[64][65];
  __shared__ float gmean[8], grstd[8];
  int b = blockIdx.z, c0 = blockIdx.y * 64, s0 = blockIdx.x * 64;
  int t = threadIdx.x;
  if (t < 8) {
    int bg = b * 32 + (c0 >> 3) + t;
    float s  = (parts[4*bg] + parts[4*bg+1]) + (parts[4*bg+2] + parts[4*bg+3]);
    float ss = (parts[256+4*bg] + parts[256+4*bg+1]) + (parts[256+4*bg+2] + parts[256+4*bg+3]);
    float mean = s * (1.0f / 32768.0f);
    float var  = ss * (1.0f / 32768.0f) - mean * mean;
    gmean[t] = mean;
    grstd[t] = rsqrtf(var + 1e-5f);
  }
  const float* xb = x + ((size_t)b * C + c0) * HW + s0;
  #pragma unroll
  for (int k = 0; k < 16; k++) {
    int e = k * 256 + t;
    int i = e >> 6, j = e & 63;
    tile[i][j] = xb[(size_t)i * HW + j];
  }
  __syncthreads();
  // tiled store: base tile (sblk = s0>>6, kblk = c0>>5)
  unsigned short* hb = h_t + (size_t)b * HW * C +
                       ((size_t)(s0 >> 6) * 8 + (c0 >> 5)) * 2048;
  #pragma unroll
  for (int k = 0; k < 16; k++) {
    int e = k * 256 + t;
    int jr = e >> 6, ir = e & 63;
    int c = c0 + ir, gl = ir >> 3;
    float v = (tile[ir][jr] - gmean[gl]) * grstd[gl] * gamma[c] + beta[c];
    hb[(ir >> 5) * 2048 + jr * 32 + (ir & 31)] = f2bf(v);
  }
}

// ---------------- QKV GEMM v3: 128x64 tiles, staged tiled operands, dbuf LDS
__global__ __launch_bounds__(256) void qkv_gemm(const unsigned short* __restrict__ wq_t,
                                                const unsigned short* __restrict__ h_t,
                                                const float* __restrict__ b_qkv,
                                                unsigned short* __restrict__ q_t,
                                                unsigned short* __restrict__ k_t,
                                                unsigned short* __restrict__ v_t) {
  int t = threadIdx.x;
  int lane = t & 63, w = t >> 6;
  int quad = lane >> 4, l16 = lane & 15;
  int m0 = blockIdx.y * 128;
  int n0 = blockIdx.x * 64;
  int b  = blockIdx.z;

  __shared__ __align__(16) unsigned short at2[2][128 * TST];
  __shared__ __align__(16) unsigned short bt2[2][64 * TST];

  const uint4* Ag = (const uint4*)(wq_t + (size_t)(blockIdx.y * 2) * 8 * 2048);
  const uint4* Bg = (const uint4*)(h_t + (size_t)b * HW * C + (size_t)blockIdx.x * 8 * 2048);
  int lrow = t >> 2, lcol = (t & 3) * 8;

  f32x4 acc[2][4];
  #pragma unroll
  for (int sl = 0; sl < 2; sl++)
    #pragma unroll
    for (int nb = 0; nb < 4; nb++) acc[sl][nb] = (f32x4){0.f, 0.f, 0.f, 0.f};

  uint4 areg0 = Ag[t];
  uint4 areg1 = Ag[8 * 256 + t];
  uint4 breg  = Bg[t];
  int phase = 0;
  for (int k = 0; k < 8; k++, phase ^= 1) {
    unsigned short* ap = &at2[phase][0];
    unsigned short* bp = &bt2[phase][0];
    *(uint2*)(ap + lrow * TST + lcol)            = make_uint2(areg0.x, areg0.y);
    *(uint2*)(ap + lrow * TST + lcol + 4)        = make_uint2(areg0.z, areg0.w);
    *(uint2*)(ap + (64 + lrow) * TST + lcol)     = make_uint2(areg1.x, areg1.y);
    *(uint2*)(ap + (64 + lrow) * TST + lcol + 4) = make_uint2(areg1.z, areg1.w);
    *(uint2*)(bp + lrow * TST + lcol)            = make_uint2(breg.x, breg.y);
    *(uint2*)(bp + lrow * TST + lcol + 4)        = make_uint2(breg.z, breg.w);
    int kn = (k < 7) ? k + 1 : 7;
    areg0 = Ag[kn * 256 + t];
    areg1 = Ag[(8 + kn) * 256 + t];
    breg  = Bg[kn * 256 + t];
    __syncthreads();
    bf16x8 a0 = load8_lds(ap + (w * 32 + l16) * TST + quad * 8);
    bf16x8 a1 = load8_lds(ap + (w * 32 + 16 + l16) * TST + quad * 8);
    #pragma unroll
    for (int nb = 0; nb < 4; nb++) {
      bf16x8 bb = load8_lds(bp + (nb * 16 + l16) * TST + quad * 8);
      acc[0][nb] = __builtin_amdgcn_mfma_f32_16x16x32_bf16(a0, bb, acc[0][nb], 0, 0, 0);
      acc[1][nb] = __builtin_amdgcn_mfma_f32_16x16x32_bf16(a1, bb, acc[1][nb], 0, 0, 0);
    }
  }

  int seg = m0 >> 8;   // 128-row blocks never straddle a Q/K/V segment
  #pragma unroll
  for (int sl = 0; sl < 2; sl++) {
    int o0 = m0 + w * 32 + sl * 16 + quad * 4;
    #pragma unroll
    for (int nb = 0; nb < 4; nb++) {
      int s = n0 + nb * 16 + l16;
      if (seg == 2) {
        #pragma unroll
        for (int r = 0; r < 4; r++)
          v_t[((size_t)b * C + ((o0 + r) - 512)) * HW + s] = f2bf(acc[sl][nb][r] + b_qkv[o0 + r]);
      } else {
        float sc = seg ? 1.0f : QSCALE;
        float v0 = (acc[sl][nb][0] + b_qkv[o0])     * sc;
        float v1 = (acc[sl][nb][1] + b_qkv[o0 + 1]) * sc;
        float v2 = (acc[sl][nb][2] + b_qkv[o0 + 2]) * sc;
        float v3 = (acc[sl][nb][3] + b_qkv[o0 + 3]) * sc;
        int oc = o0 & 255, h = oc >> 5, d = oc & 31;
        unsigned short* dst = seg ? k_t : q_t;
        uint2 dd;
        dd.x = pack_bf2(v0, v1);
        dd.y = pack_bf2(v2, v3);
        *(uint2*)(dst + (((size_t)b * NH + h) * HW + s) * HD + d) = dd;
      }
    }
  }
}

// softmax on S (one 32-key block): exp2, accumulate row-sum, and build the two
// PV B-operand fragments (keys 0..15 / 16..31) entirely in registers.
// Lane (n=query, hi) holds S[key=(r&3)+8*(r>>2)+4*hi][n] for r=0..15.
// B-fragment needs keys 8*hi+e per lane -> cross-hi exchange via permlane32_swap.
__device__ __forceinline__ void softmax_frag(const f32x16& S, f32x2& ps2,
                                             bf16x8& f0, bf16x8& f1) {
  float p[16];
  #pragma unroll
  for (int r = 0; r < 16; r++)
    p[r] = __builtin_amdgcn_exp2f(S[r]);
  f32x2 t0 = (f32x2){p[0], p[1]} + (f32x2){p[2], p[3]};
  f32x2 t1 = (f32x2){p[4], p[5]} + (f32x2){p[6], p[7]};
  f32x2 t2 = (f32x2){p[8], p[9]} + (f32x2){p[10], p[11]};
  f32x2 t3 = (f32x2){p[12], p[13]} + (f32x2){p[14], p[15]};
  ps2 += (t0 + t1) + (t2 + t3);
  unsigned int c0 = pack_bf2t(p[0],  p[1]);
  unsigned int c1 = pack_bf2t(p[2],  p[3]);
  unsigned int c2 = pack_bf2t(p[4],  p[5]);
  unsigned int c3 = pack_bf2t(p[6],  p[7]);
  unsigned int c4 = pack_bf2t(p[8],  p[9]);
  unsigned int c5 = pack_bf2t(p[10], p[11]);
  unsigned int c6 = pack_bf2t(p[12], p[13]);
  unsigned int c7 = pack_bf2t(p[14], p[15]);
  uint32x2 s02 = __builtin_amdgcn_permlane32_swap(c0, c2, false, false);
  uint32x2 s13 = __builtin_amdgcn_permlane32_swap(c1, c3, false, false);
  uint32x2 s46 = __builtin_amdgcn_permlane32_swap(c4, c6, false, false);
  uint32x2 s57 = __builtin_amdgcn_permlane32_swap(c5, c7, false, false);
  union { uint4 u; bf16x8 v; } a, b;
  a.u = make_uint4(s02.x, s13.x, s02.y, s13.y);
  b.u = make_uint4(s46.x, s57.x, s46.y, s57.y);
  f0 = a.v;
  f1 = b.v;
}

// ---------------- Flash v15 (best measured): grid (bh=16, qtile256=16, split=4);
// 64 q/wave, KVBLK=64, plain __syncthreads double-buffer loop.
__global__ __launch_bounds__(256) void flash_part(const unsigned short* __restrict__ q_t,
                                                  const unsigned short* __restrict__ k_t,
                                                  const unsigned short* __restrict__ v_t,
                                                  unsigned short* __restrict__ po,
                                                  float* __restrict__ pl,
                                                  int jspan) {
  int t = threadIdx.x;
  int lane = t & 63, w = t >> 6;
  int n = lane & 31, hi = lane >> 5, hi8 = hi * 8;
  int bh = blockIdx.x, b = bh >> 3, h = bh & 7;
  int m0 = blockIdx.y * 256 + w * 64;   // wave owns queries [m0, m0+64)
  int z = blockIdx.z;

  __shared__ __align__(16) unsigned short kt2[2][64 * KST];
  __shared__ __align__(16) unsigned short vt2[2][32 * VST];

  const unsigned short* Q  = q_t + (size_t)bh * HW * HD;
  const unsigned short* Kg = k_t + (size_t)bh * HW * HD;
  const unsigned short* Vg = v_t + ((size_t)b * C + h * HD) * HW;

  bf16x8 qa0 = load8(Q + (size_t)(m0 + n) * HD + hi8);
  bf16x8 qa1 = load8(Q + (size_t)(m0 + n) * HD + 16 + hi8);
  bf16x8 qb0 = load8(Q + (size_t)(m0 + 32 + n) * HD + hi8);
  bf16x8 qb1 = load8(Q + (size_t)(m0 + 32 + n) * HD + 16 + hi8);

  int kkey = t >> 2, kseg = (t & 3) * 8;
  int vd   = t >> 3, vseg = (t & 7) * 8;
  const unsigned short* kgp = Kg + (size_t)kkey * HD + kseg;
  const unsigned short* vgp = Vg + (size_t)vd * HW + vseg;

  f32x2 psa = (f32x2){0.f, 0.f};
  f32x2 psb = (f32x2){0.f, 0.f};
  f32x16 oTa = (f32x16){0.f,0.f,0.f,0.f,0.f,0.f,0.f,0.f,0.f,0.f,0.f,0.f,0.f,0.f,0.f,0.f};
  f32x16 oTb = (f32x16){0.f,0.f,0.f,0.f,0.f,0.f,0.f,0.f,0.f,0.f,0.f,0.f,0.f,0.f,0.f,0.f};
  const f32x16 zero16 = (f32x16){0.f,0.f,0.f,0.f,0.f,0.f,0.f,0.f,0.f,0.f,0.f,0.f,0.f,0.f,0.f,0.f};

  int jbase = z * jspan, jend = jbase + jspan;
  uint4 kreg = *(const uint4*)(kgp + (size_t)jbase * HD);
  uint4 vreg = *(const uint4*)(vgp + jbase);

  int phase = 0;
  for (int j0 = jbase; j0 < jend; j0 += 64, phase ^= 1) {
    unsigned short* ktp = &kt2[phase][0];
    unsigned short* vtp = &vt2[phase][0];
    *(uint2*)(ktp + kkey * KST + kseg)     = make_uint2(kreg.x, kreg.y);
    *(uint2*)(ktp + kkey * KST + kseg + 4) = make_uint2(kreg.z, kreg.w);
    *(uint2*)(vtp + vd * VST + vseg)       = make_uint2(vreg.x, vreg.y);
    *(uint2*)(vtp + vd * VST + vseg + 4)   = make_uint2(vreg.z, vreg.w);
    int jn = (j0 + 64 < jend) ? (j0 + 64) : jbase;
    kreg = *(const uint4*)(kgp + (size_t)jn * HD);
    vreg = *(const uint4*)(vgp + jn);
    __syncthreads();

    const unsigned short* kr0 = ktp + n * KST;
    const unsigned short* kr1 = ktp + (32 + n) * KST;
    bf16x8 ka0 = load8_lds(kr0 + hi8);
    bf16x8 ka1 = load8_lds(kr0 + 16 + hi8);
    bf16x8 kb0 = load8_lds(kr1 + hi8);
    bf16x8 kb1 = load8_lds(kr1 + 16 + hi8);

    // ---- query group a
    f32x16 S0 = __builtin_amdgcn_mfma_f32_32x32x16_bf16(ka1, qa1, zero16, 0, 0, 0);
    S0 = __builtin_amdgcn_mfma_f32_32x32x16_bf16(ka0, qa0, S0, 0, 0, 0);
    f32x16 S1 = __builtin_amdgcn_mfma_f32_32x32x16_bf16(kb1, qa1, zero16, 0, 0, 0);
    S1 = __builtin_amdgcn_mfma_f32_32x32x16_bf16(kb0, qa0, S1, 0, 0, 0);
    bf16x8 pf0, pf1, pf2, pf3;
    softmax_frag(S0, psa, pf0, pf1);
    softmax_frag(S1, psa, pf2, pf3);
    const unsigned short* vrow = vtp + n * VST;
    bf16x8 vf0 = load8_lds(vrow + hi8);
    bf16x8 vf1 = load8_lds(vrow + 16 + hi8);
    bf16x8 vf2 = load8_lds(vrow + 32 + hi8);
    bf16x8 vf3 = load8_lds(vrow + 48 + hi8);
    oTa = __builtin_amdgcn_mfma_f32_32x32x16_bf16(vf0, pf0, oTa, 0, 0, 0);
    oTa = __builtin_amdgcn_mfma_f32_32x32x16_bf16(vf1, pf1, oTa, 0, 0, 0);
    oTa = __builtin_amdgcn_mfma_f32_32x32x16_bf16(vf2, pf2, oTa, 0, 0, 0);
    oTa = __builtin_amdgcn_mfma_f32_32x32x16_bf16(vf3, pf3, oTa, 0, 0, 0);

    // ---- query group b (reuses ka*/kb*/vf* fragments)
    f32x16 T0 = __builtin_amdgcn_mfma_f32_32x32x16_bf16(ka1, qb1, zero16, 0, 0, 0);
    T0 = __builtin_amdgcn_mfma_f32_32x32x16_bf16(ka0, qb0, T0, 0, 0, 0);
    f32x16 T1 = __builtin_amdgcn_mfma_f32_32x32x16_bf16(kb1, qb1, zero16, 0, 0, 0);
    T1 = __builtin_amdgcn_mfma_f32_32x32x16_bf16(kb0, qb0, T1, 0, 0, 0);
    softmax_frag(T0, psb, pf0, pf1);
    softmax_frag(T1, psb, pf2, pf3);
    oTb = __builtin_amdgcn_mfma_f32_32x32x16_bf16(vf0, pf0, oTb, 0, 0, 0);
    oTb = __builtin_amdgcn_mfma_f32_32x32x16_bf16(vf1, pf1, oTb, 0, 0, 0);
    oTb = __builtin_amdgcn_mfma_f32_32x32x16_bf16(vf2, pf2, oTb, 0, 0, 0);
    oTb = __builtin_amdgcn_mfma_f32_32x32x16_bf16(vf3, pf3, oTb, 0, 0, 0);
  }

  float psuma = psa.x + psa.y;
  psuma += __shfl_xor(psuma, 32, 64);
  float psumb = psb.x + psb.y;
  psumb += __shfl_xor(psumb, 32, 64);

  unsigned short* pra = po + (((size_t)z * 16 + bh) * HW + (m0 + n)) * 32;
  unsigned short* prb = po + (((size_t)z * 16 + bh) * HW + (m0 + 32 + n)) * 32;
  #pragma unroll
  for (int g = 0; g < 4; g++) {
    uint2 dd;
    dd.x = pack_bf2(oTa[4 * g], oTa[4 * g + 1]);
    dd.y = pack_bf2(oTa[4 * g + 2], oTa[4 * g + 3]);
    *(uint2*)(pra + g * 8 + hi * 4) = dd;
    uint2 de;
    de.x = pack_bf2(oTb[4 * g], oTb[4 * g + 1]);
    de.y = pack_bf2(oTb[4 * g + 2], oTb[4 * g + 3]);
    *(uint2*)(prb + g * 8 + hi * 4) = de;
  }
  if (lane < 32) {
    pl[((size_t)z * 16 + bh) * HW + m0 + n] = psuma;
    pl[((size_t)z * 16 + bh) * HW + m0 + 32 + n] = psumb;
  }
}

// ---------------- Proj GEMM v3: fused split-K merge in B-staging + bias + residual
__global__ __launch_bounds__(256) void proj_gemm(const unsigned short* __restrict__ wp_t,
                                                 const unsigned short* __restrict__ po,
                                                 const float* __restrict__ pl,
                                                 const float* __restrict__ b_proj,
                                                 const float* __restrict__ x,
                                                 float* __restrict__ out) {
  int t = threadIdx.x;
  int lane = t & 63, w = t >> 6;
  int quad = lane >> 4, l16 = lane & 15;
  int m0 = blockIdx.y * 64 + w * 16;
  int n0 = blockIdx.x * 64;
  int b  = blockIdx.z;

  __shared__ __align__(16) unsigned short at2[2][64 * TST];
  __shared__ __align__(16) unsigned short bt2[2][64 * TST];

  const uint4* Ag  = (const uint4*)(wp_t + (size_t)blockIdx.y * 8 * 2048);
  const uint4* po4 = (const uint4*)po;
  int lrow = t >> 2, lcol = (t & 3) * 8;
  int s = n0 + lrow;
  const size_t zs4 = (size_t)16 * HW * 4;   // po uint4 stride per split
  const size_t zsl = (size_t)16 * HW;       // pl stride per split

  f32x4 acc[4];
  #pragma unroll
  for (int nb = 0; nb < 4; nb++) acc[nb] = (f32x4){0.f, 0.f, 0.f, 0.f};

  uint4 areg = Ag[t];
  // prefetch po/pl for k=0 (head h=0 -> bh = b*8)
  size_t pidx = ((size_t)(b * 8) * HW + s) * 4 + (t & 3);
  size_t lidx = (size_t)(b * 8) * HW + s;
  uint4 pz0 = po4[pidx];
  uint4 pz1 = po4[zs4 + pidx];
  uint4 pz2 = po4[2 * zs4 + pidx];
  uint4 pz3 = po4[3 * zs4 + pidx];
  float l0 = pl[lidx], l1 = pl[zsl + lidx], l2 = pl[2 * zsl + lidx], l3 = pl[3 * zsl + lidx];

  int phase = 0;
  for (int k = 0; k < 8; k++, phase ^= 1) {
    unsigned short* ap = &at2[phase][0];
    unsigned short* bp = &bt2[phase][0];
    *(uint2*)(ap + lrow * TST + lcol)     = make_uint2(areg.x, areg.y);
    *(uint2*)(ap + lrow * TST + lcol + 4) = make_uint2(areg.z, areg.w);
    // merge 4 split partials -> bf16 B-tile row chunk (same arithmetic/order
    // as the old merge_parts kernel)
    {
      float a[8] = {0.f,0.f,0.f,0.f,0.f,0.f,0.f,0.f};
      acc_po(pz0, a);
      acc_po(pz1, a);
      acc_po(pz2, a);
      acc_po(pz3, a);
      float inv = 1.0f / (((l0 + l1) + l2) + l3);
      uint2 d0, d1;
      d0.x = pack_bf2(a[0] * inv, a[1] * inv);
      d0.y = pack_bf2(a[2] * inv, a[3] * inv);
      d1.x = pack_bf2(a[4] * inv, a[5] * inv);
      d1.y = pack_bf2(a[6] * inv, a[7] * inv);
      *(uint2*)(bp + lrow * TST + lcol)     = d0;
      *(uint2*)(bp + lrow * TST + lcol + 4) = d1;
    }
    int kn = (k < 7) ? k + 1 : 7;
    areg = Ag[kn * 256 + t];
    size_t pidxn = ((size_t)(b * 8 + kn) * HW + s) * 4 + (t & 3);
    size_t lidxn = (size_t)(b * 8 + kn) * HW + s;
    pz0 = po4[pidxn];
    pz1 = po4[zs4 + pidxn];
    pz2 = po4[2 * zs4 + pidxn];
    pz3 = po4[3 * zs4 + pidxn];
    l0 = pl[lidxn]; l1 = pl[zsl + lidxn]; l2 = pl[2 * zsl + lidxn]; l3 = pl[3 * zsl + lidxn];
    __syncthreads();
    bf16x8 a = load8_lds(ap + (w * 16 + l16) * TST + quad * 8);
    #pragma unroll
    for (int nb = 0; nb < 4; nb++) {
      bf16x8 bb = load8_lds(bp + (nb * 16 + l16) * TST + quad * 8);
      acc[nb] = __builtin_amdgcn_mfma_f32_16x16x32_bf16(a, bb, acc[nb], 0, 0, 0);
    }
  }
  #pragma unroll
  for (int nb = 0; nb < 4; nb++) {
    int so = n0 + nb * 16 + l16;
    #pragma unroll
    for (int r = 0; r < 4; r++) {
      int o = m0 + quad * 4 + r;
      size_t idx = ((size_t)b * C + o) * HW + so;
      out[idx] = acc[nb][r] + b_proj[o] + x[idx];
    }
  }
}

extern "C" void kernel_launch(void* const* d_in, const int* in_sizes, int n_in,
                              void* d_out, int out_size, void* d_ws, size_t ws_size,
                              hipStream_t stream) {
  const float* x      = (const float*)d_in[0];
  const float* w_qkv  = (const float*)d_in[1];
  const float* b_qkv  = (const float*)d_in[2];
  const float* w_proj = (const float*)d_in[3];
  const float* b_proj = (const float*)d_in[4];
  const float* gamma  = (const float*)d_in[5];
  const float* beta   = (const float*)d_in[6];
  float* out = (float*)d_out;

  char* ws = (char*)d_ws;
  float*          parts = (float*)ws;                          // 2 KB
  unsigned short* wq_t  = (unsigned short*)(ws + 4096);        // 384 KB (tiled)
  unsigned short* wp_t  = (unsigned short*)(ws + 397312);      // 128 KB (tiled)
  unsigned short* h_t   = (unsigned short*)(ws + 528384);      // 4 MB tiled
  unsigned short* q_t   = (unsigned short*)(ws + 4722688);     // 4 MB [bh][s][d]
  unsigned short* k_t   = (unsigned short*)(ws + 8916992);     // 4 MB [bh][s][d]
  unsigned short* v_t   = (unsigned short*)(ws + 13111296);    // 4 MB [b][c][s]
  unsigned short* po    = (unsigned short*)(ws + 17305600);    // 16 MB (4 splits, bf16)
  float*          pl    = (float*)(ws + 34082816);             // 1 MB (4 splits)

  gn_stats_part<<<512, 256, 0, stream>>>(x, parts, w_qkv, w_proj, wq_t, wp_t);
  gn_apply<<<dim3(64, 4, 2), 256, 0, stream>>>(x, parts, gamma, beta, h_t);
  qkv_gemm<<<dim3(64, 6, 2), 256, 0, stream>>>(wq_t, h_t, b_qkv, q_t, k_t, v_t);
  flash_part<<<dim3(16, 16, NSPLIT), 256, 0, stream>>>(q_t, k_t, v_t, po, pl, HW / NSPLIT);
  proj_gemm<<<dim3(64, 4, 2), 256, 0, stream>>>(wp_t, po, pl, b_proj, x, out);
}